// Round 7
// baseline (306.065 us; speedup 1.0000x reference)
//
#include <hip/hip_runtime.h>
#include <math.h>

#define NC    512
#define NG    4
#define NCG   128          // C / G
#define NR    16           // reduced dim
#define NTOPK 384
#define NB    16
#define HW    (112 * 112)  // 12544
#define ALPHA 0.1f
#define EPSC  1e-8f

#define CHUNK     4                  // batches per chunk (103 MB)
#define NCHUNK    (NB / CHUNK)       // 4
#define BC_PER_CH (CHUNK * NC)       // 2048 tiles per chunk

typedef float f32x4 __attribute__((ext_vector_type(4)));

// ---- P(ch): pool chunk ch. Cached loads allocate the chunk in L3. ----
__global__ __launch_bounds__(256) void pool_chunk(
    const float* __restrict__ x, float* __restrict__ avg_out,
    float* __restrict__ max_out, int ch) {
  const int bc = ch * BC_PER_CH + (int)blockIdx.x;
  const int t = threadIdx.x;
  const f32x4* p = reinterpret_cast<const f32x4*>(x + (size_t)bc * HW);
  float s = 0.f;
  float m = -INFINITY;
  for (int i = t; i < 3072; i += 1024) {
    f32x4 v0 = p[i];
    f32x4 v1 = p[i + 256];
    f32x4 v2 = p[i + 512];
    f32x4 v3 = p[i + 768];
    s += (v0.x + v0.y) + (v0.z + v0.w);
    s += (v1.x + v1.y) + (v1.z + v1.w);
    s += (v2.x + v2.y) + (v2.z + v2.w);
    s += (v3.x + v3.y) + (v3.z + v3.w);
    m = fmaxf(m, fmaxf(fmaxf(v0.x, v0.y), fmaxf(v0.z, v0.w)));
    m = fmaxf(m, fmaxf(fmaxf(v1.x, v1.y), fmaxf(v1.z, v1.w)));
    m = fmaxf(m, fmaxf(fmaxf(v2.x, v2.y), fmaxf(v2.z, v2.w)));
    m = fmaxf(m, fmaxf(fmaxf(v3.x, v3.y), fmaxf(v3.z, v3.w)));
  }
  if (t < 64) {
    f32x4 v = p[3072 + t];
    s += (v.x + v.y) + (v.z + v.w);
    m = fmaxf(m, fmaxf(fmaxf(v.x, v.y), fmaxf(v.z, v.w)));
  }
  #pragma unroll
  for (int off = 32; off > 0; off >>= 1) {
    s += __shfl_down(s, off, 64);
    m = fmaxf(m, __shfl_down(m, off, 64));
  }
  __shared__ float ss[4], sm[4];
  const int wave = t >> 6, lane = t & 63;
  if (lane == 0) { ss[wave] = s; sm[wave] = m; }
  __syncthreads();
  if (t == 0) {
    float st = (ss[0] + ss[1]) + (ss[2] + ss[3]);
    float mt = fmaxf(fmaxf(sm[0], sm[1]), fmaxf(sm[2], sm[3]));
    avg_out[bc] = st / (float)HW;
    max_out[bc] = mt;
  }
}

// ---- M(ch): blend for the 4 batches of chunk ch (1 block per batch) ----
__global__ __launch_bounds__(512) void mask_chunk(
    const float* __restrict__ avg, const float* __restrict__ mx,
    const float* __restrict__ W1, const float* __restrict__ b1,
    const float* __restrict__ W2, const float* __restrict__ b2,
    const float* __restrict__ noise_u, float* __restrict__ blend, int ch) {
  const int b = ch * CHUNK + (int)blockIdx.x;
  const int t = threadIdx.x;  // 0..511 (= channel)
  __shared__ float comb[2 * NC];
  __shared__ float h[NG * NR];
  __shared__ float sc[NC];
  comb[t]      = avg[b * NC + t];
  comb[NC + t] = mx[b * NC + t];
  __syncthreads();
  if (t < NG * NR) {
    const int g = t / NR, r = t % NR;
    float acc = b1[g * NR + r];
    const float* w  = W1 + (size_t)g * (2 * NCG) * NR + r;
    const float* cf = comb + g * (2 * NCG);
    #pragma unroll 8
    for (int i = 0; i < 2 * NCG; ++i) acc += cf[i] * w[i * NR];
    h[t] = fmaxf(acc, 0.f);
  }
  __syncthreads();
  {
    const int g = t / NCG, o = t % NCG;
    float acc = b2[g * NCG + o];
    const float* w  = W2 + (size_t)g * NR * NCG + o;
    const float* hh = h + g * NR;
    #pragma unroll
    for (int r = 0; r < NR; ++r) acc += hh[r] * w[r * NCG];
    sc[t] = acc;
  }
  __syncthreads();
  const float my = sc[t];
  int cnt = 0;
  for (int j = 0; j < NC; ++j) {
    float v = sc[j];
    cnt += (v > my) || (v == my && j < t);
  }
  const float hard = (cnt < NTOPK) ? 1.f : 0.f;
  const float u = noise_u[b * NC + t];
  const float gum = -logf(-logf(u + EPSC) + EPSC);
  const float soft = 1.f / (1.f + expf(-(my + gum) * 2.0f));  // TAU=0.5
  const float mask = hard * soft;
  blend[b * NC + t] = mask + (1.f - mask) * ALPHA;
}

// ---- S(ch): scale chunk ch. Reads same order as P(ch) => L3 hits. ----
__global__ __launch_bounds__(256) void scale_chunk(
    const float* __restrict__ x, const float* __restrict__ blend,
    float* __restrict__ out, int ch) {
  const int bc = ch * BC_PER_CH + (int)blockIdx.x;
  const int t = threadIdx.x;
  const float s = blend[bc];
  const f32x4* p = reinterpret_cast<const f32x4*>(x + (size_t)bc * HW);
  f32x4* q = reinterpret_cast<f32x4*>(out + (size_t)bc * HW);
  for (int i = t; i < 3072; i += 1024) {
    f32x4 v0 = p[i];
    f32x4 v1 = p[i + 256];
    f32x4 v2 = p[i + 512];
    f32x4 v3 = p[i + 768];
    v0 *= s; v1 *= s; v2 *= s; v3 *= s;
    __builtin_nontemporal_store(v0, &q[i]);
    __builtin_nontemporal_store(v1, &q[i + 256]);
    __builtin_nontemporal_store(v2, &q[i + 512]);
    __builtin_nontemporal_store(v3, &q[i + 768]);
  }
  if (t < 64) {
    const int i = 3072 + t;
    f32x4 v = p[i];
    v *= s;
    __builtin_nontemporal_store(v, &q[i]);
  }
}

extern "C" void kernel_launch(void* const* d_in, const int* in_sizes, int n_in,
                              void* d_out, int out_size, void* d_ws, size_t ws_size,
                              hipStream_t stream) {
  const float* x       = (const float*)d_in[0];
  const float* W1      = (const float*)d_in[1];
  const float* b1      = (const float*)d_in[2];
  const float* W2      = (const float*)d_in[3];
  const float* b2      = (const float*)d_in[4];
  const float* noise_u = (const float*)d_in[5];
  float* out = (float*)d_out;

  float* ws_avg   = (float*)d_ws;              // B*C floats
  float* ws_max   = ws_avg + NB * NC;          // B*C floats
  float* ws_blend = ws_max + NB * NC;          // B*C floats

  for (int ch = 0; ch < NCHUNK; ++ch) {
    pool_chunk<<<BC_PER_CH, 256, 0, stream>>>(x, ws_avg, ws_max, ch);
    mask_chunk<<<CHUNK, 512, 0, stream>>>(ws_avg, ws_max, W1, b1, W2, b2,
                                          noise_u, ws_blend, ch);
    scale_chunk<<<BC_PER_CH, 256, 0, stream>>>(x, ws_blend, out, ch);
  }
}